// Round 1
// baseline (90.223 us; speedup 1.0000x reference)
//
#include <hip/hip_runtime.h>
#include <hip/hip_bf16.h>

// GraphLSTM fused kernel for MI355X.
// Key observations:
//  - f-gate of the LSTM is unused by the reference -> skip 1/4 of W_ih/b_ih/b_hh reads.
//  - O=1 conv is linear -> fold into per-edge scalar: out[b,dst] += ew * dot(conv_w, h_new[b,e,:]).
//  - One wave (64 lanes) per edge: W_ih[e] loaded once into registers, reused across B=8 batches.

#define MN 1024
#define BB 8
#define DD 8
#define HH 64

__device__ __forceinline__ float fsig(float x) {
    // 1 / (1 + e^-x); safe for all x (exp->inf => rcp->0 => 1 is wrong side? no:
    // x large pos: exp(-x)->0 -> rcp(1)=1 OK; x large neg: exp(-x)->inf -> rcp(inf)=0 OK)
    return __builtin_amdgcn_rcpf(1.0f + __expf(-x));
}
__device__ __forceinline__ float ftanh(float x) {
    float t = fminf(fmaxf(2.0f * x, -30.0f), 30.0f);   // clamp: avoid inf/inf
    float e = __expf(t);
    return (e - 1.0f) * __builtin_amdgcn_rcpf(e + 1.0f);
}

// Prep: transpose x (B,D,MN) -> xt (MN,B,D) and init out = conv_b.
__global__ void prep_kernel(const float* __restrict__ x,
                            const float* __restrict__ conv_b,
                            float* __restrict__ xt,
                            float* __restrict__ out) {
    int tid = blockIdx.x * 256 + threadIdx.x;   // 65536 threads
    if (tid < MN * BB * DD) {
        int mn = tid >> 6;          // /64
        int b  = (tid >> 3) & 7;
        int d  = tid & 7;
        xt[tid] = x[b * (DD * MN) + d * MN + mn];
    }
    if (tid < BB * MN) out[tid] = conv_b[0];
}

// One wave per edge.
__global__ __launch_bounds__(256) void edge_kernel(
        const float* __restrict__ xt,      // (MN, B, D)
        const float* __restrict__ edge_w,  // (E)
        const float* __restrict__ W,       // (E, 256, 8)
        const float* __restrict__ b_ih,    // (E, 256)
        const float* __restrict__ b_hh,    // (E, 256)
        const float* __restrict__ conv_w,  // (1, 64)
        const int*   __restrict__ src_idx,
        const int*   __restrict__ dst_idx,
        float* __restrict__ out,           // (B, MN), pre-initialized to conv_b
        int E) {
    int wave = blockIdx.x * 4 + (threadIdx.x >> 6);
    if (wave >= E) return;
    int lane = threadIdx.x & 63;
    int e = wave;

    int src = src_idx[e];
    int dst = dst_idx[e];
    float ew = edge_w[e];

    int m    = lane >> 1;   // h index base (0..31)
    int half = lane & 1;    // which d-half (0: d0-3, 1: d4-7)

    // ---- Load W fragments: compacted float4 index cf4 = lane + 64k, k=0..5,
    // skipping the unused f-gate chunk (global f4 in [128,256)).
    const float4* Wf = (const float4*)(W + (size_t)e * 2048);
    float4 w[6];
#pragma unroll
    for (int k = 0; k < 6; ++k) {
        int cf4 = lane + 64 * k;                    // 0..383
        int f4  = cf4 + (cf4 >= 128 ? 128 : 0);     // skip f-chunk
        w[k] = Wf[f4];
    }

    // ---- Biases: compacted gate cg = m + 32k; global gate = cg + (cg>=64 ? 64 : 0).
    // k=0,1 -> i (h=m, m+32); k=2,3 -> g; k=4,5 -> o.
    float bias[6];
    const float* bi = b_ih + (size_t)e * 256;
    const float* bh = b_hh + (size_t)e * 256;
#pragma unroll
    for (int k = 0; k < 6; ++k) {
        int cg = m + 32 * k;
        int gg = cg + (cg >= 64 ? 64 : 0);
        bias[k] = bi[gg] + bh[gg];
    }

    float cwA = conv_w[m];
    float cwB = conv_w[m + 32];

    const float4* xte = (const float4*)(xt + (size_t)src * 64);

#pragma unroll
    for (int b = 0; b < BB; ++b) {
        float4 xv = xte[b * 2 + half];   // x[b, half*4 .. half*4+3] at node src (L1/L2 hit)
        float p[6];
#pragma unroll
        for (int k = 0; k < 6; ++k) {
            p[k] = w[k].x * xv.x + w[k].y * xv.y + w[k].z * xv.z + w[k].w * xv.w;
            p[k] += __shfl_xor(p[k], 1, 64);   // combine d-halves across lane pair
            p[k] += bias[k];
        }
        // LSTM (no f-gate in reference): c = sig(i)*tanh(g); h = sig(o)*tanh(c)
        float cA = fsig(p[0]) * ftanh(p[2]);
        float hA = fsig(p[4]) * ftanh(cA);
        float cB = fsig(p[1]) * ftanh(p[3]);
        float hB = fsig(p[5]) * ftanh(cB);
        float s = cwA * hA + cwB * hB;
        // Reduce over the 32 distinct pairs (lanes within a pair hold duplicates,
        // so start the butterfly at offset 2 -> result is the true sum).
#pragma unroll
        for (int off = 2; off < 64; off <<= 1) s += __shfl_xor(s, off, 64);
        if (lane == 0) atomicAdd(out + b * MN + dst, ew * s);
    }
}

extern "C" void kernel_launch(void* const* d_in, const int* in_sizes, int n_in,
                              void* d_out, int out_size, void* d_ws, size_t ws_size,
                              hipStream_t stream) {
    const float* x      = (const float*)d_in[0];
    const float* edge_w = (const float*)d_in[1];
    const float* W_ih   = (const float*)d_in[2];
    const float* b_ih   = (const float*)d_in[3];
    const float* b_hh   = (const float*)d_in[4];
    const float* conv_w = (const float*)d_in[5];
    const float* conv_b = (const float*)d_in[6];
    const int* src_idx  = (const int*)d_in[7];
    const int* dst_idx  = (const int*)d_in[8];
    int E = in_sizes[1];

    float* xt  = (float*)d_ws;      // 65536 floats = 256 KB
    float* out = (float*)d_out;     // 8192 floats

    prep_kernel<<<256, 256, 0, stream>>>(x, conv_b, xt, out);

    int blocks = (E + 3) / 4;       // 4 waves (edges) per 256-thread block
    edge_kernel<<<blocks, 256, 0, stream>>>(xt, edge_w, W_ih, b_ih, b_hh,
                                            conv_w, src_idx, dst_idx, out, E);
}

// Round 2
// 85.487 us; speedup vs baseline: 1.0554x; 1.0554x over previous
//
#include <hip/hip_runtime.h>
#include <hip/hip_bf16.h>

// GraphLSTM fused kernel for MI355X — R1: lane=h layout.
//  - f-gate unused by reference -> skip 1/4 of W_ih/b_ih/b_hh reads.
//  - O=1 conv folded into per-edge scalar: out[b,dst] += ew * dot(conv_w, h_new[b,e,:]).
//  - One wave per edge, lane = hidden index h: no shuffles in the dot (x is
//    wave-uniform broadcast), 4 exp + 4 rcp per lane per batch (no duplication).
//  - 8-batch reduction over 64 lanes via batch-folding butterfly: 10 shuffles
//    total, one 8-lane-active atomic instruction per wave.

#define MN 1024
#define BB 8
#define DD 8
#define HH 64

__device__ __forceinline__ float fsig(float x) {
    // x>>0: exp(-x)->0 -> 1. x<<0: exp(-x)->inf -> rcp -> 0. Safe.
    return __builtin_amdgcn_rcpf(1.0f + __expf(-x));
}
__device__ __forceinline__ float ftanh(float x) {
    float t = fminf(fmaxf(2.0f * x, -30.0f), 30.0f);   // avoid inf/inf
    float e = __expf(t);
    return (e - 1.0f) * __builtin_amdgcn_rcpf(e + 1.0f);
}
__device__ __forceinline__ float dot8(const float4& a0, const float4& a1,
                                      const float4& b0, const float4& b1) {
    float r;
    r = a0.x * b0.x;
    r = fmaf(a0.y, b0.y, r);
    r = fmaf(a0.z, b0.z, r);
    r = fmaf(a0.w, b0.w, r);
    r = fmaf(a1.x, b1.x, r);
    r = fmaf(a1.y, b1.y, r);
    r = fmaf(a1.z, b1.z, r);
    r = fmaf(a1.w, b1.w, r);
    return r;
}

// Prep: transpose x (B,D,MN) -> xt (MN,B,D) and init out = conv_b.
__global__ void prep_kernel(const float* __restrict__ x,
                            const float* __restrict__ conv_b,
                            float* __restrict__ xt,
                            float* __restrict__ out) {
    int tid = blockIdx.x * 256 + threadIdx.x;   // 65536 threads
    if (tid < MN * BB * DD) {
        int mn = tid >> 6;          // /64
        int b  = (tid >> 3) & 7;
        int d  = tid & 7;
        xt[tid] = x[b * (DD * MN) + d * MN + mn];
    }
    if (tid < BB * MN) out[tid] = conv_b[0];
}

// One wave per edge, lane = h.
__global__ __launch_bounds__(256) void edge_kernel(
        const float* __restrict__ xt,      // (MN, B, D)
        const float* __restrict__ edge_w,  // (E)
        const float* __restrict__ W,       // (E, 256, 8)
        const float* __restrict__ b_ih,    // (E, 256)
        const float* __restrict__ b_hh,    // (E, 256)
        const float* __restrict__ conv_w,  // (1, 64)
        const int*   __restrict__ src_idx,
        const int*   __restrict__ dst_idx,
        float* __restrict__ out,           // (B, MN), pre-initialized to conv_b
        int E) {
    int wid  = threadIdx.x >> 6;
    int lane = threadIdx.x & 63;
    int e = __builtin_amdgcn_readfirstlane(blockIdx.x * 4 + wid);
    if (e >= E) return;

    int src  = src_idx[e];      // SGPR (uniform addr) -> s_load
    int dst  = dst_idx[e];
    float ew = edge_w[e];

    // ---- W rows for this h: gates i (rows 0-63), g (128-191), o (192-255).
    const float* We = W + (size_t)e * 2048;
    const float4* Wi = (const float4*)(We + lane * 8);            // 2 x float4
    const float4* Wg = (const float4*)(We + 1024 + lane * 8);
    const float4* Wo = (const float4*)(We + 1536 + lane * 8);
    float4 wi0 = Wi[0], wi1 = Wi[1];
    float4 wg0 = Wg[0], wg1 = Wg[1];
    float4 wo0 = Wo[0], wo1 = Wo[1];

    // ---- Biases (coalesced: 64 consecutive floats per load).
    const float* bi = b_ih + (size_t)e * 256;
    const float* bh = b_hh + (size_t)e * 256;
    float bI = bi[lane]       + bh[lane];
    float bG = bi[128 + lane] + bh[128 + lane];
    float bO = bi[192 + lane] + bh[192 + lane];
    float cw = conv_w[lane];

    const float* xe = xt + (size_t)src * 64;   // 64 floats, wave-uniform, cached

    float s[BB];
#pragma unroll
    for (int b = 0; b < BB; ++b) {
        float4 xlo = *(const float4*)(xe + b * 8);       // broadcast loads
        float4 xhi = *(const float4*)(xe + b * 8 + 4);
        float pi = bI + dot8(wi0, wi1, xlo, xhi);
        float pg = bG + dot8(wg0, wg1, xlo, xhi);
        float po = bO + dot8(wo0, wo1, xlo, xhi);
        float c  = fsig(pi) * ftanh(pg);
        float h  = fsig(po) * ftanh(c);
        s[b] = cw * h;
    }

    // ---- Batch-folding reduction over the 64 lanes (Σ_h), 10 shuffles.
    // After fold k, lane bit (5,4,3) selects which batch this lane carries.
    float u[4];
#pragma unroll
    for (int k = 0; k < 4; ++k) {
        float keep = (lane & 32) ? s[k + 4] : s[k];
        float send = (lane & 32) ? s[k]     : s[k + 4];
        u[k] = keep + __shfl_xor(send, 32, 64);
    }
    float v[2];
#pragma unroll
    for (int k = 0; k < 2; ++k) {
        float keep = (lane & 16) ? u[k + 2] : u[k];
        float send = (lane & 16) ? u[k]     : u[k + 2];
        v[k] = keep + __shfl_xor(send, 16, 64);
    }
    float keep = (lane & 8) ? v[1] : v[0];
    float send = (lane & 8) ? v[0] : v[1];
    float t = keep + __shfl_xor(send, 8, 64);
    t += __shfl_xor(t, 4, 64);
    t += __shfl_xor(t, 2, 64);
    t += __shfl_xor(t, 1, 64);
    // lane = 8*batch + r; r==0 lanes do one 8-lane-active atomic instruction.
    if ((lane & 7) == 0) {
        int b = lane >> 3;
        atomicAdd(out + b * MN + dst, ew * t);
    }
}

extern "C" void kernel_launch(void* const* d_in, const int* in_sizes, int n_in,
                              void* d_out, int out_size, void* d_ws, size_t ws_size,
                              hipStream_t stream) {
    const float* x      = (const float*)d_in[0];
    const float* edge_w = (const float*)d_in[1];
    const float* W_ih   = (const float*)d_in[2];
    const float* b_ih   = (const float*)d_in[3];
    const float* b_hh   = (const float*)d_in[4];
    const float* conv_w = (const float*)d_in[5];
    const float* conv_b = (const float*)d_in[6];
    const int* src_idx  = (const int*)d_in[7];
    const int* dst_idx  = (const int*)d_in[8];
    int E = in_sizes[1];

    float* xt  = (float*)d_ws;      // 65536 floats = 256 KB
    float* out = (float*)d_out;     // 8192 floats

    prep_kernel<<<256, 256, 0, stream>>>(x, conv_b, xt, out);

    int blocks = (E + 3) / 4;       // 4 waves (edges) per 256-thread block
    edge_kernel<<<blocks, 256, 0, stream>>>(xt, edge_w, W_ih, b_ih, b_hh,
                                            conv_w, src_idx, dst_idx, out, E);
}

// Round 3
// 73.115 us; speedup vs baseline: 1.2340x; 1.1692x over previous
//
#include <hip/hip_runtime.h>
#include <hip/hip_bf16.h>

// GraphLSTM fused kernel for MI355X — R2: persistent waves + cross-edge
// 2-deep software pipeline.
//  - f-gate unused by reference -> skip 1/4 of W_ih/b_ih/b_hh reads.
//  - O=1 conv folded into per-edge scalar: out[b,dst] += ew * dot(conv_w, h).
//  - One wave per edge-slice, lane = hidden index h; grid-stride over edges
//    with ping-pong register buffers so each wave always has the NEXT edge's
//    12 HBM loads in flight while computing the current edge (latency hiding
//    at 4 waves/SIMD).

#define MN 1024
#define BB 8

__device__ __forceinline__ float fsig(float x) {
    return __builtin_amdgcn_rcpf(1.0f + __expf(-x));
}
__device__ __forceinline__ float ftanh(float x) {
    float t = fminf(fmaxf(2.0f * x, -30.0f), 30.0f);   // avoid inf/inf
    float e = __expf(t);
    return (e - 1.0f) * __builtin_amdgcn_rcpf(e + 1.0f);
}
__device__ __forceinline__ float dot8(const float4& a0, const float4& a1,
                                      const float4& b0, const float4& b1) {
    float r;
    r = a0.x * b0.x;
    r = fmaf(a0.y, b0.y, r);
    r = fmaf(a0.z, b0.z, r);
    r = fmaf(a0.w, b0.w, r);
    r = fmaf(a1.x, b1.x, r);
    r = fmaf(a1.y, b1.y, r);
    r = fmaf(a1.z, b1.z, r);
    r = fmaf(a1.w, b1.w, r);
    return r;
}

// Prep: transpose x (B,D,MN) -> xt (MN,B,D) and init out = conv_b.
__global__ void prep_kernel(const float* __restrict__ x,
                            const float* __restrict__ conv_b,
                            float* __restrict__ xt,
                            float* __restrict__ out) {
    int tid = blockIdx.x * 256 + threadIdx.x;   // 65536 threads
    if (tid < MN * BB * 8) {
        int mn = tid >> 6;
        int b  = (tid >> 3) & 7;
        int d  = tid & 7;
        xt[tid] = x[b * (8 * MN) + d * MN + mn];
    }
    if (tid < BB * MN) out[tid] = conv_b[0];
}

struct EdgeRegs {
    float4 wi0, wi1, wg0, wg1, wo0, wo1;   // 24 VGPR
    float  bIi, bIh, bGi, bGh, bOi, bOh;   // 6 VGPR (raw; adds sink to compute)
    float  ew;                              // uniform -> SGPR
    int    src, dst;                        // uniform -> SGPR
};

__device__ __forceinline__ void prefetch(EdgeRegs& r, int e_,
        const float* __restrict__ W, const float* __restrict__ b_ih,
        const float* __restrict__ b_hh, const float* __restrict__ edge_w,
        const int* __restrict__ src_idx, const int* __restrict__ dst_idx,
        int lane) {
    int e = __builtin_amdgcn_readfirstlane(e_);
    const float* We = W + (size_t)e * 2048 + lane * 8;
    r.wi0 = *(const float4*)(We);
    r.wi1 = *(const float4*)(We + 4);
    r.wg0 = *(const float4*)(We + 1024);
    r.wg1 = *(const float4*)(We + 1028);
    r.wo0 = *(const float4*)(We + 1536);
    r.wo1 = *(const float4*)(We + 1540);
    const float* bi = b_ih + (size_t)e * 256 + lane;
    const float* bh = b_hh + (size_t)e * 256 + lane;
    r.bIi = bi[0];   r.bIh = bh[0];
    r.bGi = bi[128]; r.bGh = bh[128];
    r.bOi = bi[192]; r.bOh = bh[192];
    r.ew  = edge_w[e];
    r.src = src_idx[e];
    r.dst = dst_idx[e];
}

__device__ __forceinline__ void compute(const EdgeRegs& r,
        const float* __restrict__ xt, float cw, float* __restrict__ out,
        int lane) {
    const float* xe = xt + (size_t)r.src * 64;   // uniform addr -> scalar cache
    float bI = r.bIi + r.bIh;
    float bG = r.bGi + r.bGh;
    float bO = r.bOi + r.bOh;
    float s[BB];
#pragma unroll
    for (int b = 0; b < BB; ++b) {
        float4 xlo = *(const float4*)(xe + b * 8);
        float4 xhi = *(const float4*)(xe + b * 8 + 4);
        float pi = bI + dot8(r.wi0, r.wi1, xlo, xhi);
        float pg = bG + dot8(r.wg0, r.wg1, xlo, xhi);
        float po = bO + dot8(r.wo0, r.wo1, xlo, xhi);
        float c  = fsig(pi) * ftanh(pg);
        float h  = fsig(po) * ftanh(c);
        s[b] = cw * h;
    }
    // Batch-folding reduction over 64 lanes (Σ_h), 10 shuffles total.
    float u[4];
#pragma unroll
    for (int k = 0; k < 4; ++k) {
        float keep = (lane & 32) ? s[k + 4] : s[k];
        float send = (lane & 32) ? s[k]     : s[k + 4];
        u[k] = keep + __shfl_xor(send, 32, 64);
    }
    float v[2];
#pragma unroll
    for (int k = 0; k < 2; ++k) {
        float keep = (lane & 16) ? u[k + 2] : u[k];
        float send = (lane & 16) ? u[k]     : u[k + 2];
        v[k] = keep + __shfl_xor(send, 16, 64);
    }
    float keep = (lane & 8) ? v[1] : v[0];
    float send = (lane & 8) ? v[0] : v[1];
    float t = keep + __shfl_xor(send, 8, 64);
    t += __shfl_xor(t, 4, 64);
    t += __shfl_xor(t, 2, 64);
    t += __shfl_xor(t, 1, 64);
    if ((lane & 7) == 0) {
        int b = lane >> 3;
        atomicAdd(out + b * MN + r.dst, r.ew * t);
    }
}

__global__ __launch_bounds__(256, 4) void edge_kernel(
        const float* __restrict__ xt,      // (MN, B, D)
        const float* __restrict__ edge_w,  // (E)
        const float* __restrict__ W,       // (E, 256, 8)
        const float* __restrict__ b_ih,    // (E, 256)
        const float* __restrict__ b_hh,    // (E, 256)
        const float* __restrict__ conv_w,  // (1, 64)
        const int*   __restrict__ src_idx,
        const int*   __restrict__ dst_idx,
        float* __restrict__ out,           // (B, MN), pre-initialized to conv_b
        int E) {
    int lane = threadIdx.x & 63;
    int nw = gridDim.x * 4;                       // total waves
    int e  = blockIdx.x * 4 + (threadIdx.x >> 6); // this wave's first edge
    if (e >= E) return;
    float cw = conv_w[lane];

    EdgeRegs A, B;
    prefetch(A, e, W, b_ih, b_hh, edge_w, src_idx, dst_idx, lane);
    int en = e + nw;
    while (true) {
        if (en < E) prefetch(B, en, W, b_ih, b_hh, edge_w, src_idx, dst_idx, lane);
        compute(A, xt, cw, out, lane);
        e = en; if (e >= E) break;
        en = e + nw;
        if (en < E) prefetch(A, en, W, b_ih, b_hh, edge_w, src_idx, dst_idx, lane);
        compute(B, xt, cw, out, lane);
        e = en; if (e >= E) break;
        en = e + nw;
    }
}

extern "C" void kernel_launch(void* const* d_in, const int* in_sizes, int n_in,
                              void* d_out, int out_size, void* d_ws, size_t ws_size,
                              hipStream_t stream) {
    const float* x      = (const float*)d_in[0];
    const float* edge_w = (const float*)d_in[1];
    const float* W_ih   = (const float*)d_in[2];
    const float* b_ih   = (const float*)d_in[3];
    const float* b_hh   = (const float*)d_in[4];
    const float* conv_w = (const float*)d_in[5];
    const float* conv_b = (const float*)d_in[6];
    const int* src_idx  = (const int*)d_in[7];
    const int* dst_idx  = (const int*)d_in[8];
    int E = in_sizes[1];

    float* xt  = (float*)d_ws;      // 65536 floats = 256 KB
    float* out = (float*)d_out;     // 8192 floats

    prep_kernel<<<256, 256, 0, stream>>>(x, conv_b, xt, out);

    edge_kernel<<<1024, 256, 0, stream>>>(xt, edge_w, W_ih, b_ih, b_hh,
                                          conv_w, src_idx, dst_idx, out, E);
}